// Round 3
// baseline (43.739 us; speedup 1.0000x reference)
//
#include <hip/hip_runtime.h>
#include <math.h>

#define PI_F 3.14159265358979323846f

// ---------------------------------------------------------------------------
// Amplitude-per-lane 4-qubit simulator, fused with the FC + log_softmax head.
//
// 16 lanes = 1 circuit (one 2x2 patch); lane holds ONE complex amplitude.
// CNOTs are GF(2)-linear index maps folded into a compile-time lane
// relabeling f: partner lane = l ^ f^{-1}(e_p) (compile-time shfl_xor mask),
// row-select = parity(l & F[p]) (compile-time AND mask, applied via a
// per-lane precomputed 16-bit parity table P).
//
// Grid: 64 images x 13 sub-blocks = 832 blocks x 256 threads.
// Block (b, sb) simulates circuits pi = sb*16 .. sb*16+15 (pi<196), reduces
// their FC contribution to 10 partial logits, writes partials[b][sb][10],
// then atomically bumps cnt[b]; the 13th arriver per image sums the 13
// partials in fixed order (bit-deterministic) and emits log_softmax.
// ---------------------------------------------------------------------------

struct Gates { int xm[84]; int sm[84]; int fin[4]; };

constexpr Gates make_gates() {
  Gates gt{};
  int F[4] = {1, 2, 4, 8};   // F[p]: bit_p(f(l)) = parity(l & F[p])
  int H[4] = {1, 2, 4, 8};   // rows of f^{-1}
  int ng = 0;
  auto cnot = [&](int c, int t) {
    const int pc = 3 - c, pt = 3 - t;
    F[pt] ^= F[pc];
    for (int p = 0; p < 4; ++p)
      if (H[p] & (1 << pt)) H[p] ^= (1 << pc);
  };
  auto gate = [&](int w) {
    const int p = 3 - w;
    int m = 0;
    for (int q = 0; q < 4; ++q)
      if (H[q] & (1 << p)) m |= 1 << q;   // m = f^{-1}(e_p)
    gt.xm[ng] = m; gt.sm[ng] = F[p]; ++ng;
  };
  for (int step = 0; step < 20; ++step)
    for (int j = 0; j < 4; ++j) {
      gate(j);
      cnot(0, 1); cnot(1, 2); cnot(2, 3); cnot(3, 0);
    }
  // RandomLayers stand-in: rx@3, ry@1, CNOT(0,2), rz@0, rx@2, CNOT(1,3)
  gate(3); gate(1); cnot(0, 2); gate(0); gate(2); cnot(1, 3);
  for (int p = 0; p < 4; ++p) gt.fin[p] = F[p];
  return gt;
}

constexpr Gates GT = make_gates();

// Rot-symmetric gate: u00=(WR,WI), u01=(XR,XI), u10=(-XR,XI), u11=(WR,-WI).
// Row select = bit sm[K] of per-lane parity table P -> sign flip of WI, XR.
#define APPLY_GATE(K, WR, WI, XR, XI) do {                                    \
    const float pre_ = __shfl_xor(re, GT.xm[K]);                              \
    const float pim_ = __shfl_xor(im, GT.xm[K]);                              \
    const unsigned sb_ = ((P >> GT.sm[K]) & 1u) << 31;                        \
    const float cmi_ = __uint_as_float(__float_as_uint(WI) ^ sb_);            \
    const float cpr_ = __uint_as_float(__float_as_uint(XR) ^ sb_);            \
    const float nre_ = (WR)*re - cmi_*im + cpr_*pre_ - (XI)*pim_;             \
    const float nim_ = (WR)*im + cmi_*re + cpr_*pim_ + (XI)*pre_;             \
    re = nre_; im = nim_;                                                     \
  } while (0)

__global__ __launch_bounds__(256) void qcnn_fused_kernel(
    const float* __restrict__ images,   // (64,1,28,28)
    const float* __restrict__ rp,       // (4,)
    const float* __restrict__ fcw,      // (10,784)
    const float* __restrict__ fcb,      // (10,)
    float* __restrict__ out,            // (64,10)
    int*   __restrict__ cnt,            // (64,)  zeroed per launch
    float* __restrict__ partials)       // (64,13,10)
{
  const int tid = threadIdx.x;
  const int B   = blockIdx.x;
  const int b   = B / 13;               // image
  const int sb  = B - b * 13;           // sub-block within image
  const int grp = tid >> 4;
  const int l16 = tid & 15;
  const int pi  = sb * 16 + grp;        // patch index (0..207; active if <196)
  const bool active = (pi < 196);

  // Per-lane parity table: bit_m(P) = parity(l16 & m).
  unsigned P = 0;
  if (l16 & 1) P ^= 0xAAAAu;
  if (l16 & 2) P ^= 0xCCCCu;
  if (l16 & 4) P ^= 0xF0F0u;
  if (l16 & 8) P ^= 0xFF00u;

  float val = 0.f;   // this lane's FC feature value (ev_{l16} for l16<4)

  if (active) {
    const int pj = pi / 14;
    const int pk = pi - pj * 14;
    const float* img = images + b * 784 + (2 * pj) * 28 + 2 * pk;
    float px[4];
    px[0] = img[0]  * PI_F;
    px[1] = img[1]  * PI_F;
    px[2] = img[28] * PI_F;
    px[3] = img[29] * PI_F;

    // 4 distinct Rot matrices (GROUP_IDX period 4).
    float wr[4], wi[4], xr[4], xi[4];
    {
      const int GIphi[4] = {0, 3, 2, 1};
      const int GIth [4] = {1, 0, 3, 2};
      const int GIom [4] = {2, 1, 0, 3};
#pragma unroll
      for (int g = 0; g < 4; ++g) {
        const float phi = px[GIphi[g]], th = px[GIth[g]], om = px[GIom[g]];
        const float a = 0.5f * (phi + om), d = 0.5f * (phi - om), h = 0.5f * th;
        const float sa = __sinf(a), ca = __cosf(a);
        const float sd = __sinf(d), cd = __cosf(d);
        const float st = __sinf(h), ct = __cosf(h);
        wr[g] =  ca * ct;  wi[g] = -sa * ct;   // u00
        xr[g] = -cd * st;  xi[g] = -sd * st;   // u01
      }
    }

    float re = (l16 == 0) ? 1.f : 0.f;
    float im = 0.f;

#pragma unroll
    for (int step = 0; step < 20; ++step) {
      const int g = step & 3;
#pragma unroll
      for (int j = 0; j < 4; ++j) {
        const int k = step * 4 + j;
        APPLY_GATE(k, wr[g], wi[g], xr[g], xi[g]);
      }
    }

    // Final gates 80..83: RX(rp0)@3, RY(rp1)@1, RZ(rp2)@0, RX(rp3)@2.
    {
      const float s0 = __sinf(0.5f * rp[0]), c0 = __cosf(0.5f * rp[0]);
      APPLY_GATE(80, c0, 0.f, 0.f, -s0);
      const float s1 = __sinf(0.5f * rp[1]), c1 = __cosf(0.5f * rp[1]);
      APPLY_GATE(81, c1, 0.f, -s1, 0.f);
      const float s2 = __sinf(0.5f * rp[2]), c2 = __cosf(0.5f * rp[2]);
      APPLY_GATE(82, c2, -s2, 0.f, 0.f);
      const float s3 = __sinf(0.5f * rp[3]), c3 = __cosf(0.5f * rp[3]);
      APPLY_GATE(83, c3, 0.f, 0.f, -s3);
    }

    // PauliZ expvals; sign for wire j = parity(l & fin[3-j]).
    const float pr = re * re + im * im;
    float e0 = __uint_as_float(__float_as_uint(pr) ^ (((P >> GT.fin[3]) & 1u) << 31));
    float e1 = __uint_as_float(__float_as_uint(pr) ^ (((P >> GT.fin[2]) & 1u) << 31));
    float e2 = __uint_as_float(__float_as_uint(pr) ^ (((P >> GT.fin[1]) & 1u) << 31));
    float e3 = __uint_as_float(__float_as_uint(pr) ^ (((P >> GT.fin[0]) & 1u) << 31));
#pragma unroll
    for (int s = 1; s < 16; s <<= 1) {
      e0 += __shfl_xor(e0, s);
      e1 += __shfl_xor(e1, s);
      e2 += __shfl_xor(e2, s);
      e3 += __shfl_xor(e3, s);
    }
    val = (l16 == 0) ? e0 : (l16 == 1) ? e1 : (l16 == 2) ? e2 : (l16 == 3) ? e3 : 0.f;
  }

  // ---- FC partial: acc_o = sum over this block's circuits of val * w[o][f] ----
  float acc[10];
  if (l16 < 4) {
    const int fidx = pi * 4 + l16;      // < 832 <= 7839, always in-bounds
#pragma unroll
    for (int o = 0; o < 10; ++o) acc[o] = val * fcw[o * 784 + fidx];
  } else {
#pragma unroll
    for (int o = 0; o < 10; ++o) acc[o] = 0.f;
  }
  // Reduce over the wave: fold 4 groups (masks 16,32), then j-lanes (1,2).
#pragma unroll
  for (int o = 0; o < 10; ++o) {
    acc[o] += __shfl_xor(acc[o], 16);
    acc[o] += __shfl_xor(acc[o], 32);
    acc[o] += __shfl_xor(acc[o], 1);
    acc[o] += __shfl_xor(acc[o], 2);
  }

  __shared__ float wacc[4][10];
  __shared__ int lastflag;
  const int wid = tid >> 6;
  if ((tid & 63) == 0) {
#pragma unroll
    for (int o = 0; o < 10; ++o) wacc[wid][o] = acc[o];
  }
  __syncthreads();
  if (tid < 10) {
    const float ps = wacc[0][tid] + wacc[1][tid] + wacc[2][tid] + wacc[3][tid];
    partials[(b * 13 + sb) * 10 + tid] = ps;
  }
  __syncthreads();   // partial stores drained (vmcnt(0) before barrier)

  if (tid == 0) {
    __threadfence();                       // release
    const int old = atomicAdd(&cnt[b], 1); // device-scope
    lastflag = (old == 12);
  }
  __syncthreads();

  if (lastflag) {                          // block-uniform branch
    __threadfence();                       // acquire
    if (tid < 16) {
      float lgv = -1e30f;
      if (tid < 10) {
        float s = fcb[tid];
#pragma unroll
        for (int k = 0; k < 13; ++k) s += partials[(b * 13 + k) * 10 + tid];
        lgv = s;
      }
      float mx = lgv;
#pragma unroll
      for (int s = 1; s < 16; s <<= 1) mx = fmaxf(mx, __shfl_xor(mx, s));
      float ex = (tid < 10) ? __expf(lgv - mx) : 0.f;
      float se = ex;
#pragma unroll
      for (int s = 1; s < 16; s <<= 1) se += __shfl_xor(se, s);
      if (tid < 10) out[b * 10 + tid] = lgv - mx - __logf(se);
    }
  }
}

// ---------------------------------------------------------------------------

extern "C" void kernel_launch(void* const* d_in, const int* in_sizes, int n_in,
                              void* d_out, int out_size, void* d_ws, size_t ws_size,
                              hipStream_t stream) {
  const float* images = (const float*)d_in[0];   // 64*1*28*28
  const float* rp     = (const float*)d_in[1];   // 4
  const float* fcw    = (const float*)d_in[2];   // 10*784
  const float* fcb    = (const float*)d_in[3];   // 10
  float* out = (float*)d_out;                    // 64*10

  int*   cnt      = (int*)d_ws;                  // 64 ints
  float* partials = (float*)d_ws + 64;           // 64*13*10 floats

  hipMemsetAsync(cnt, 0, 64 * sizeof(int), stream);
  qcnn_fused_kernel<<<832, 256, 0, stream>>>(images, rp, fcw, fcb, out, cnt, partials);
}

// Round 4
// 25.607 us; speedup vs baseline: 1.7080x; 1.7080x over previous
//
#include <hip/hip_runtime.h>
#include <math.h>

#define PI_F 3.14159265358979323846f

// ---------------------------------------------------------------------------
// Amplitude-per-lane 4-qubit simulator, fused with the FC + log_softmax head.
//
// 16 lanes = 1 circuit (one 2x2 patch); lane holds ONE complex amplitude.
// CNOTs are GF(2)-linear index maps folded into a compile-time lane
// relabeling f: partner lane = l ^ f^{-1}(e_p) (compile-time shfl_xor mask),
// row-select = parity(l & F[p]) (compile-time AND mask, applied via a
// per-lane precomputed 16-bit parity table P).
//
// Grid: 64 images x 13 sub-blocks = 832 blocks x 256 threads.
// Block (b, sb) simulates circuits pi = sb*16 .. sb*16+15 (pi<196), reduces
// their FC contribution to 10 partial logits, publishes partials[b][sb][10]
// via RELAXED AGENT-SCOPE atomic stores (cache-bypassing, no L2 flush — the
// round-3 __threadfence caused per-block buffer_wbl2/inv L2 flushes = 43 us),
// bumps cnt[b] (relaxed agent atomicAdd, ordered by the vmcnt(0) hipcc emits
// before s_barrier); the 13th arriver sums the 13 partials in fixed order
// (bit-deterministic) and emits log_softmax.
// ---------------------------------------------------------------------------

struct Gates { int xm[84]; int sm[84]; int fin[4]; };

constexpr Gates make_gates() {
  Gates gt{};
  int F[4] = {1, 2, 4, 8};   // F[p]: bit_p(f(l)) = parity(l & F[p])
  int H[4] = {1, 2, 4, 8};   // rows of f^{-1}
  int ng = 0;
  auto cnot = [&](int c, int t) {
    const int pc = 3 - c, pt = 3 - t;
    F[pt] ^= F[pc];
    for (int p = 0; p < 4; ++p)
      if (H[p] & (1 << pt)) H[p] ^= (1 << pc);
  };
  auto gate = [&](int w) {
    const int p = 3 - w;
    int m = 0;
    for (int q = 0; q < 4; ++q)
      if (H[q] & (1 << p)) m |= 1 << q;   // m = f^{-1}(e_p)
    gt.xm[ng] = m; gt.sm[ng] = F[p]; ++ng;
  };
  for (int step = 0; step < 20; ++step)
    for (int j = 0; j < 4; ++j) {
      gate(j);
      cnot(0, 1); cnot(1, 2); cnot(2, 3); cnot(3, 0);
    }
  // RandomLayers stand-in: rx@3, ry@1, CNOT(0,2), rz@0, rx@2, CNOT(1,3)
  gate(3); gate(1); cnot(0, 2); gate(0); gate(2); cnot(1, 3);
  for (int p = 0; p < 4; ++p) gt.fin[p] = F[p];
  return gt;
}

constexpr Gates GT = make_gates();

// Rot-symmetric gate: u00=(WR,WI), u01=(XR,XI), u10=(-XR,XI), u11=(WR,-WI).
// Row select = bit sm[K] of per-lane parity table P -> sign flip of WI, XR.
#define APPLY_GATE(K, WR, WI, XR, XI) do {                                    \
    const float pre_ = __shfl_xor(re, GT.xm[K]);                              \
    const float pim_ = __shfl_xor(im, GT.xm[K]);                              \
    const unsigned sb_ = ((P >> GT.sm[K]) & 1u) << 31;                        \
    const float cmi_ = __uint_as_float(__float_as_uint(WI) ^ sb_);            \
    const float cpr_ = __uint_as_float(__float_as_uint(XR) ^ sb_);            \
    const float nre_ = (WR)*re - cmi_*im + cpr_*pre_ - (XI)*pim_;             \
    const float nim_ = (WR)*im + cmi_*re + cpr_*pim_ + (XI)*pre_;             \
    re = nre_; im = nim_;                                                     \
  } while (0)

__global__ __launch_bounds__(256) void qcnn_fused_kernel(
    const float* __restrict__ images,   // (64,1,28,28)
    const float* __restrict__ rp,       // (4,)
    const float* __restrict__ fcw,      // (10,784)
    const float* __restrict__ fcb,      // (10,)
    float* __restrict__ out,            // (64,10)
    int*   __restrict__ cnt,            // (64,)  zeroed per launch
    float* __restrict__ partials)       // (64,13,10)
{
  const int tid = threadIdx.x;
  const int B   = blockIdx.x;
  const int b   = B / 13;               // image
  const int sb  = B - b * 13;           // sub-block within image
  const int grp = tid >> 4;
  const int l16 = tid & 15;
  const int pi  = sb * 16 + grp;        // patch index (0..207; active if <196)
  const bool active = (pi < 196);

  // Per-lane parity table: bit_m(P) = parity(l16 & m).
  unsigned P = 0;
  if (l16 & 1) P ^= 0xAAAAu;
  if (l16 & 2) P ^= 0xCCCCu;
  if (l16 & 4) P ^= 0xF0F0u;
  if (l16 & 8) P ^= 0xFF00u;

  float val = 0.f;   // this lane's FC feature value (ev_{l16} for l16<4)

  if (active) {
    const int pj = pi / 14;
    const int pk = pi - pj * 14;
    const float* img = images + b * 784 + (2 * pj) * 28 + 2 * pk;
    float px[4];
    px[0] = img[0]  * PI_F;
    px[1] = img[1]  * PI_F;
    px[2] = img[28] * PI_F;
    px[3] = img[29] * PI_F;

    // 4 distinct Rot matrices (GROUP_IDX period 4).
    float wr[4], wi[4], xr[4], xi[4];
    {
      const int GIphi[4] = {0, 3, 2, 1};
      const int GIth [4] = {1, 0, 3, 2};
      const int GIom [4] = {2, 1, 0, 3};
#pragma unroll
      for (int g = 0; g < 4; ++g) {
        const float phi = px[GIphi[g]], th = px[GIth[g]], om = px[GIom[g]];
        const float a = 0.5f * (phi + om), d = 0.5f * (phi - om), h = 0.5f * th;
        const float sa = __sinf(a), ca = __cosf(a);
        const float sd = __sinf(d), cd = __cosf(d);
        const float st = __sinf(h), ct = __cosf(h);
        wr[g] =  ca * ct;  wi[g] = -sa * ct;   // u00
        xr[g] = -cd * st;  xi[g] = -sd * st;   // u01
      }
    }

    float re = (l16 == 0) ? 1.f : 0.f;
    float im = 0.f;

#pragma unroll
    for (int step = 0; step < 20; ++step) {
      const int g = step & 3;
#pragma unroll
      for (int j = 0; j < 4; ++j) {
        const int k = step * 4 + j;
        APPLY_GATE(k, wr[g], wi[g], xr[g], xi[g]);
      }
    }

    // Final gates 80..83: RX(rp0)@3, RY(rp1)@1, RZ(rp2)@0, RX(rp3)@2.
    {
      const float s0 = __sinf(0.5f * rp[0]), c0 = __cosf(0.5f * rp[0]);
      APPLY_GATE(80, c0, 0.f, 0.f, -s0);
      const float s1 = __sinf(0.5f * rp[1]), c1 = __cosf(0.5f * rp[1]);
      APPLY_GATE(81, c1, 0.f, -s1, 0.f);
      const float s2 = __sinf(0.5f * rp[2]), c2 = __cosf(0.5f * rp[2]);
      APPLY_GATE(82, c2, -s2, 0.f, 0.f);
      const float s3 = __sinf(0.5f * rp[3]), c3 = __cosf(0.5f * rp[3]);
      APPLY_GATE(83, c3, 0.f, 0.f, -s3);
    }

    // PauliZ expvals; sign for wire j = parity(l & fin[3-j]).
    const float pr = re * re + im * im;
    float e0 = __uint_as_float(__float_as_uint(pr) ^ (((P >> GT.fin[3]) & 1u) << 31));
    float e1 = __uint_as_float(__float_as_uint(pr) ^ (((P >> GT.fin[2]) & 1u) << 31));
    float e2 = __uint_as_float(__float_as_uint(pr) ^ (((P >> GT.fin[1]) & 1u) << 31));
    float e3 = __uint_as_float(__float_as_uint(pr) ^ (((P >> GT.fin[0]) & 1u) << 31));
#pragma unroll
    for (int s = 1; s < 16; s <<= 1) {
      e0 += __shfl_xor(e0, s);
      e1 += __shfl_xor(e1, s);
      e2 += __shfl_xor(e2, s);
      e3 += __shfl_xor(e3, s);
    }
    val = (l16 == 0) ? e0 : (l16 == 1) ? e1 : (l16 == 2) ? e2 : (l16 == 3) ? e3 : 0.f;
  }

  // ---- FC partial: acc_o = sum over this block's circuits of val * w[o][f] ----
  float acc[10];
  if (l16 < 4) {
    const int fidx = pi * 4 + l16;      // < 832 <= 7839, always in-bounds
#pragma unroll
    for (int o = 0; o < 10; ++o) acc[o] = val * fcw[o * 784 + fidx];
  } else {
#pragma unroll
    for (int o = 0; o < 10; ++o) acc[o] = 0.f;
  }
  // Reduce over the wave: fold 4 groups (masks 16,32), then j-lanes (1,2).
#pragma unroll
  for (int o = 0; o < 10; ++o) {
    acc[o] += __shfl_xor(acc[o], 16);
    acc[o] += __shfl_xor(acc[o], 32);
    acc[o] += __shfl_xor(acc[o], 1);
    acc[o] += __shfl_xor(acc[o], 2);
  }

  __shared__ float wacc[4][10];
  __shared__ int lastflag;
  const int wid = tid >> 6;
  if ((tid & 63) == 0) {
#pragma unroll
    for (int o = 0; o < 10; ++o) wacc[wid][o] = acc[o];
  }
  __syncthreads();

  // Publish partials with relaxed agent-scope atomic stores (cache-bypassing,
  // device-coherent, NO fence/L2-flush).
  if (tid < 10) {
    const float ps = wacc[0][tid] + wacc[1][tid] + wacc[2][tid] + wacc[3][tid];
    __hip_atomic_store(&partials[(b * 13 + sb) * 10 + tid], ps,
                       __ATOMIC_RELAXED, __HIP_MEMORY_SCOPE_AGENT);
  }
  // hipcc emits s_waitcnt vmcnt(0) before s_barrier -> the stores above are
  // device-visible before any thread passes this barrier.
  __syncthreads();

  if (tid == 0) {
    const int old = __hip_atomic_fetch_add(&cnt[b], 1,
                        __ATOMIC_RELAXED, __HIP_MEMORY_SCOPE_AGENT);
    lastflag = (old == 12);
  }
  __syncthreads();

  if (lastflag) {                          // block-uniform branch
    if (tid < 16) {
      float lgv = -1e30f;
      if (tid < 10) {
        float s = fcb[tid];
#pragma unroll
        for (int k = 0; k < 13; ++k)
          s += __hip_atomic_load(&partials[(b * 13 + k) * 10 + tid],
                                 __ATOMIC_RELAXED, __HIP_MEMORY_SCOPE_AGENT);
        lgv = s;
      }
      float mx = lgv;
#pragma unroll
      for (int s = 1; s < 16; s <<= 1) mx = fmaxf(mx, __shfl_xor(mx, s));
      float ex = (tid < 10) ? __expf(lgv - mx) : 0.f;
      float se = ex;
#pragma unroll
      for (int s = 1; s < 16; s <<= 1) se += __shfl_xor(se, s);
      if (tid < 10) out[b * 10 + tid] = lgv - mx - __logf(se);
    }
  }
}

// ---------------------------------------------------------------------------

extern "C" void kernel_launch(void* const* d_in, const int* in_sizes, int n_in,
                              void* d_out, int out_size, void* d_ws, size_t ws_size,
                              hipStream_t stream) {
  const float* images = (const float*)d_in[0];   // 64*1*28*28
  const float* rp     = (const float*)d_in[1];   // 4
  const float* fcw    = (const float*)d_in[2];   // 10*784
  const float* fcb    = (const float*)d_in[3];   // 10
  float* out = (float*)d_out;                    // 64*10

  int*   cnt      = (int*)d_ws;                  // 64 ints
  float* partials = (float*)d_ws + 64;           // 64*13*10 floats

  hipMemsetAsync(cnt, 0, 64 * sizeof(int), stream);
  qcnn_fused_kernel<<<832, 256, 0, stream>>>(images, rp, fcw, fcb, out, cnt, partials);
}

// Round 5
// 21.570 us; speedup vs baseline: 2.0277x; 1.1871x over previous
//
#include <hip/hip_runtime.h>
#include <math.h>

#define PI_F 3.14159265358979323846f

// ---------------------------------------------------------------------------
// Amplitude-per-lane 4-qubit simulator + per-block FC partial reduction.
//
// 16 lanes = 1 circuit (one 2x2 patch); lane holds ONE complex amplitude.
// CNOTs are GF(2)-linear index maps folded into a compile-time lane
// relabeling f: partner lane = l ^ f^{-1}(e_p) (compile-time shfl_xor mask),
// row-select = parity(l & F[p]) (compile-time AND mask, applied via a
// per-lane precomputed 16-bit parity table P).
//
// Kernel 1: 64 images x 13 sub-blocks = 832 blocks x 256 threads.
// Block (b, sb) simulates circuits pi = sb*16 .. sb*16+15 (pi<196), reduces
// their FC contribution to 10 partial logits, stores partials[b][sb][10]
// with PLAIN stores (no atomics/fences — round 3/4 showed cross-block
// coordination costs more than a second dispatch: threadfence L2-flush
// = 43 us, relaxed-atomic variant = 25.6 us, plain 2-kernel = 19.7 us).
// Kernel 2: 64 blocks x 64 threads; sums 13 partials in fixed order
// (bit-deterministic), adds bias, emits log_softmax.
// ---------------------------------------------------------------------------

struct Gates { int xm[84]; int sm[84]; int fin[4]; };

constexpr Gates make_gates() {
  Gates gt{};
  int F[4] = {1, 2, 4, 8};   // F[p]: bit_p(f(l)) = parity(l & F[p])
  int H[4] = {1, 2, 4, 8};   // rows of f^{-1}
  int ng = 0;
  auto cnot = [&](int c, int t) {
    const int pc = 3 - c, pt = 3 - t;
    F[pt] ^= F[pc];
    for (int p = 0; p < 4; ++p)
      if (H[p] & (1 << pt)) H[p] ^= (1 << pc);
  };
  auto gate = [&](int w) {
    const int p = 3 - w;
    int m = 0;
    for (int q = 0; q < 4; ++q)
      if (H[q] & (1 << p)) m |= 1 << q;   // m = f^{-1}(e_p)
    gt.xm[ng] = m; gt.sm[ng] = F[p]; ++ng;
  };
  for (int step = 0; step < 20; ++step)
    for (int j = 0; j < 4; ++j) {
      gate(j);
      cnot(0, 1); cnot(1, 2); cnot(2, 3); cnot(3, 0);
    }
  // RandomLayers stand-in: rx@3, ry@1, CNOT(0,2), rz@0, rx@2, CNOT(1,3)
  gate(3); gate(1); cnot(0, 2); gate(0); gate(2); cnot(1, 3);
  for (int p = 0; p < 4; ++p) gt.fin[p] = F[p];
  return gt;
}

constexpr Gates GT = make_gates();

// Rot-symmetric gate: u00=(WR,WI), u01=(XR,XI), u10=(-XR,XI), u11=(WR,-WI).
// Row select = bit sm[K] of per-lane parity table P -> sign flip of WI, XR.
#define APPLY_GATE(K, WR, WI, XR, XI) do {                                    \
    const float pre_ = __shfl_xor(re, GT.xm[K]);                              \
    const float pim_ = __shfl_xor(im, GT.xm[K]);                              \
    const unsigned sb_ = ((P >> GT.sm[K]) & 1u) << 31;                        \
    const float cmi_ = __uint_as_float(__float_as_uint(WI) ^ sb_);            \
    const float cpr_ = __uint_as_float(__float_as_uint(XR) ^ sb_);            \
    const float nre_ = (WR)*re - cmi_*im + cpr_*pre_ - (XI)*pim_;             \
    const float nim_ = (WR)*im + cmi_*re + cpr_*pim_ + (XI)*pre_;             \
    re = nre_; im = nim_;                                                     \
  } while (0)

__global__ __launch_bounds__(256) void qcnn_circuit_kernel(
    const float* __restrict__ images,   // (64,1,28,28)
    const float* __restrict__ rp,       // (4,)
    const float* __restrict__ fcw,      // (10,784)
    float* __restrict__ partials)       // (64,13,10)
{
  const int tid = threadIdx.x;
  const int B   = blockIdx.x;
  const int b   = B / 13;               // image
  const int sb  = B - b * 13;           // sub-block within image
  const int grp = tid >> 4;
  const int l16 = tid & 15;
  const int pi  = sb * 16 + grp;        // patch index (0..207; active if <196)
  const bool active = (pi < 196);

  // Per-lane parity table: bit_m(P) = parity(l16 & m).
  unsigned P = 0;
  if (l16 & 1) P ^= 0xAAAAu;
  if (l16 & 2) P ^= 0xCCCCu;
  if (l16 & 4) P ^= 0xF0F0u;
  if (l16 & 8) P ^= 0xFF00u;

  float val = 0.f;   // this lane's FC feature value (ev_{l16} for l16<4)

  if (active) {
    const int pj = pi / 14;
    const int pk = pi - pj * 14;
    const float* img = images + b * 784 + (2 * pj) * 28 + 2 * pk;
    float px[4];
    px[0] = img[0]  * PI_F;
    px[1] = img[1]  * PI_F;
    px[2] = img[28] * PI_F;
    px[3] = img[29] * PI_F;

    // 4 distinct Rot matrices (GROUP_IDX period 4).
    float wr[4], wi[4], xr[4], xi[4];
    {
      const int GIphi[4] = {0, 3, 2, 1};
      const int GIth [4] = {1, 0, 3, 2};
      const int GIom [4] = {2, 1, 0, 3};
#pragma unroll
      for (int g = 0; g < 4; ++g) {
        const float phi = px[GIphi[g]], th = px[GIth[g]], om = px[GIom[g]];
        const float a = 0.5f * (phi + om), d = 0.5f * (phi - om), h = 0.5f * th;
        const float sa = __sinf(a), ca = __cosf(a);
        const float sd = __sinf(d), cd = __cosf(d);
        const float st = __sinf(h), ct = __cosf(h);
        wr[g] =  ca * ct;  wi[g] = -sa * ct;   // u00
        xr[g] = -cd * st;  xi[g] = -sd * st;   // u01
      }
    }

    float re = (l16 == 0) ? 1.f : 0.f;
    float im = 0.f;

#pragma unroll
    for (int step = 0; step < 20; ++step) {
      const int g = step & 3;
#pragma unroll
      for (int j = 0; j < 4; ++j) {
        const int k = step * 4 + j;
        APPLY_GATE(k, wr[g], wi[g], xr[g], xi[g]);
      }
    }

    // Final gates 80..83: RX(rp0)@3, RY(rp1)@1, RZ(rp2)@0, RX(rp3)@2.
    {
      const float s0 = __sinf(0.5f * rp[0]), c0 = __cosf(0.5f * rp[0]);
      APPLY_GATE(80, c0, 0.f, 0.f, -s0);
      const float s1 = __sinf(0.5f * rp[1]), c1 = __cosf(0.5f * rp[1]);
      APPLY_GATE(81, c1, 0.f, -s1, 0.f);
      const float s2 = __sinf(0.5f * rp[2]), c2 = __cosf(0.5f * rp[2]);
      APPLY_GATE(82, c2, -s2, 0.f, 0.f);
      const float s3 = __sinf(0.5f * rp[3]), c3 = __cosf(0.5f * rp[3]);
      APPLY_GATE(83, c3, 0.f, 0.f, -s3);
    }

    // PauliZ expvals; sign for wire j = parity(l & fin[3-j]).
    const float pr = re * re + im * im;
    float e0 = __uint_as_float(__float_as_uint(pr) ^ (((P >> GT.fin[3]) & 1u) << 31));
    float e1 = __uint_as_float(__float_as_uint(pr) ^ (((P >> GT.fin[2]) & 1u) << 31));
    float e2 = __uint_as_float(__float_as_uint(pr) ^ (((P >> GT.fin[1]) & 1u) << 31));
    float e3 = __uint_as_float(__float_as_uint(pr) ^ (((P >> GT.fin[0]) & 1u) << 31));
#pragma unroll
    for (int s = 1; s < 16; s <<= 1) {
      e0 += __shfl_xor(e0, s);
      e1 += __shfl_xor(e1, s);
      e2 += __shfl_xor(e2, s);
      e3 += __shfl_xor(e3, s);
    }
    val = (l16 == 0) ? e0 : (l16 == 1) ? e1 : (l16 == 2) ? e2 : (l16 == 3) ? e3 : 0.f;
  }

  // ---- FC partial: acc_o = sum over this block's circuits of val * w[o][f] ----
  float acc[10];
  if (l16 < 4) {
    const int fidx = pi * 4 + l16;      // < 832 <= 7839, always in-bounds
#pragma unroll
    for (int o = 0; o < 10; ++o) acc[o] = val * fcw[o * 784 + fidx];
  } else {
#pragma unroll
    for (int o = 0; o < 10; ++o) acc[o] = 0.f;
  }
  // Reduce over the wave: fold 4 groups (masks 16,32), then j-lanes (1,2).
#pragma unroll
  for (int o = 0; o < 10; ++o) {
    acc[o] += __shfl_xor(acc[o], 16);
    acc[o] += __shfl_xor(acc[o], 32);
    acc[o] += __shfl_xor(acc[o], 1);
    acc[o] += __shfl_xor(acc[o], 2);
  }

  __shared__ float wacc[4][10];
  const int wid = tid >> 6;
  if ((tid & 63) == 0) {
#pragma unroll
    for (int o = 0; o < 10; ++o) wacc[wid][o] = acc[o];
  }
  __syncthreads();
  if (tid < 10) {
    const float ps = wacc[0][tid] + wacc[1][tid] + wacc[2][tid] + wacc[3][tid];
    partials[(b * 13 + sb) * 10 + tid] = ps;   // plain store, stream-ordered
  }
}

// ---------------------------------------------------------------------------
// Finisher: sum 13 partials per (image, class), bias, log_softmax.
// ---------------------------------------------------------------------------
__global__ __launch_bounds__(64) void qcnn_fc_kernel(
    const float* __restrict__ partials,  // (64,13,10)
    const float* __restrict__ fcb,       // (10,)
    float* __restrict__ out)             // (64,10)
{
  const int b   = blockIdx.x;
  const int tid = threadIdx.x;
  if (tid >= 16) return;

  float lgv = -1e30f;
  if (tid < 10) {
    float s = fcb[tid];
#pragma unroll
    for (int k = 0; k < 13; ++k) s += partials[(b * 13 + k) * 10 + tid];
    lgv = s;
  }
  float mx = lgv;
#pragma unroll
  for (int s = 1; s < 16; s <<= 1) mx = fmaxf(mx, __shfl_xor(mx, s));
  float ex = (tid < 10) ? __expf(lgv - mx) : 0.f;
  float se = ex;
#pragma unroll
  for (int s = 1; s < 16; s <<= 1) se += __shfl_xor(se, s);
  if (tid < 10) out[b * 10 + tid] = lgv - mx - __logf(se);
}

// ---------------------------------------------------------------------------

extern "C" void kernel_launch(void* const* d_in, const int* in_sizes, int n_in,
                              void* d_out, int out_size, void* d_ws, size_t ws_size,
                              hipStream_t stream) {
  const float* images = (const float*)d_in[0];   // 64*1*28*28
  const float* rp     = (const float*)d_in[1];   // 4
  const float* fcw    = (const float*)d_in[2];   // 10*784
  const float* fcb    = (const float*)d_in[3];   // 10
  float* out = (float*)d_out;                    // 64*10
  float* partials = (float*)d_ws;                // 64*13*10 floats = 33 KB

  qcnn_circuit_kernel<<<832, 256, 0, stream>>>(images, rp, fcw, partials);
  qcnn_fc_kernel<<<64, 64, 0, stream>>>(partials, fcb, out);
}

// Round 6
// 20.920 us; speedup vs baseline: 2.0907x; 1.0311x over previous
//
#include <hip/hip_runtime.h>
#include <math.h>

#define PI_F 3.14159265358979323846f

// ---------------------------------------------------------------------------
// Amplitude-per-lane 4-qubit simulator + per-block FC partial reduction.
//
// 16 lanes = 1 circuit; lane holds ONE complex amplitude. CNOTs fold into a
// compile-time lane relabeling f (GF(2)-linear); gate k exchanges with lane
// l ^ xm[k] and sign-selects by parity(l & sm[k]).
//
// ROUND-6 CHANGE: the wave-shuffles were ds_swizzle ops saturating the ONE
// per-CU LDS pipe (~224 ops/wave x 13 waves/CU x ~5.8cyc ~= 5.3us). All xor
// masks <=15 decompose into DPP primitives (quad_perm xor1/2/3,
// row_half_mirror=xor7, row_mirror=xor15) which run on the VALU (4 SIMDs/CU).
// Gate masks {9,10,11} stay on LDS for pipe balance. The FC tail is folded:
// per-lane signed pr feeds the FC dot directly, 16-lane DPP-add reduce, rows
// write wrow[16][10] in LDS. LDS-pipe ops/wave ~224 -> ~34.
// ---------------------------------------------------------------------------

struct Gates { int xm[84]; int sm[84]; int fin[4]; };

constexpr Gates make_gates() {
  Gates gt{};
  int F[4] = {1, 2, 4, 8};   // F[p]: bit_p(f(l)) = parity(l & F[p])
  int H[4] = {1, 2, 4, 8};   // rows of f^{-1}
  int ng = 0;
  auto cnot = [&](int c, int t) {
    const int pc = 3 - c, pt = 3 - t;
    F[pt] ^= F[pc];
    for (int p = 0; p < 4; ++p)
      if (H[p] & (1 << pt)) H[p] ^= (1 << pc);
  };
  auto gate = [&](int w) {
    const int p = 3 - w;
    int m = 0;
    for (int q = 0; q < 4; ++q)
      if (H[q] & (1 << p)) m |= 1 << q;   // m = f^{-1}(e_p)
    gt.xm[ng] = m; gt.sm[ng] = F[p]; ++ng;
  };
  for (int step = 0; step < 20; ++step)
    for (int j = 0; j < 4; ++j) {
      gate(j);
      cnot(0, 1); cnot(1, 2); cnot(2, 3); cnot(3, 0);
    }
  // RandomLayers stand-in: rx@3, ry@1, CNOT(0,2), rz@0, rx@2, CNOT(1,3)
  gate(3); gate(1); cnot(0, 2); gate(0); gate(2); cnot(1, 3);
  for (int p = 0; p < 4; ++p) gt.fin[p] = F[p];
  return gt;
}

constexpr Gates GT = make_gates();

// ---- DPP-based xor-shuffle (VALU pipe) ------------------------------------
template <int CTRL>
__device__ __forceinline__ float dppmov(float v) {
  return __int_as_float(
      __builtin_amdgcn_mov_dpp(__float_as_int(v), CTRL, 0xF, 0xF, true));
}

// xor-exchange across lanes. Masks decompose: bit3 -> row_mirror(xor15),
// then bit2 -> row_half_mirror(xor7), then quad_perm for residual {1,2,3}.
// {9,10,11} (3-chain) stay on the LDS pipe (__shfl_xor) for pipe balance.
template <int M>
__device__ __forceinline__ float sxor(float v) {
  if constexpr (M == 0) return v;
  else if constexpr (M == 9 || M == 10 || M == 11) return __shfl_xor(v, M);
  else if constexpr ((M & 8) != 0) return sxor<M ^ 15>(dppmov<0x140>(v)); // xor15
  else if constexpr ((M & 4) != 0) return sxor<M ^ 7>(dppmov<0x141>(v));  // xor7
  else if constexpr (M == 1) return dppmov<0xB1>(v);   // quad_perm [1,0,3,2]
  else if constexpr (M == 2) return dppmov<0x4E>(v);   // quad_perm [2,3,0,1]
  else return dppmov<0x1B>(v);                          // quad_perm [3,2,1,0]
}

// Rot-symmetric gate: u00=(WR,WI), u01=(XR,XI), u10=(-XR,XI), u11=(WR,-WI).
template <int XM, int SM>
__device__ __forceinline__ void apply_gate(float& re, float& im, unsigned P,
                                           float WR, float WI, float XR, float XI) {
  const float pre = sxor<XM>(re);
  const float pim = sxor<XM>(im);
  const unsigned sb = ((P >> SM) & 1u) << 31;
  const float cmi = __uint_as_float(__float_as_uint(WI) ^ sb);
  const float cpr = __uint_as_float(__float_as_uint(XR) ^ sb);
  const float nre = WR * re - cmi * im + cpr * pre - XI * pim;
  const float nim = WR * im + cmi * re + cpr * pim + XI * pre;
  re = nre; im = nim;
}

// Compile-time-unrolled 80-gate main loop (masks must be template args).
template <int K>
struct Loop80 {
  static __device__ __forceinline__ void run(float& re, float& im, unsigned P,
      const float (&wr)[4], const float (&wi)[4],
      const float (&xr)[4], const float (&xi)[4]) {
    constexpr int g = (K >> 2) & 3;
    apply_gate<GT.xm[K], GT.sm[K]>(re, im, P, wr[g], wi[g], xr[g], xi[g]);
    Loop80<K + 1>::run(re, im, P, wr, wi, xr, xi);
  }
};
template <>
struct Loop80<80> {
  static __device__ __forceinline__ void run(float&, float&, unsigned,
      const float (&)[4], const float (&)[4],
      const float (&)[4], const float (&)[4]) {}
};

__global__ __launch_bounds__(256) void qcnn_circuit_kernel(
    const float* __restrict__ images,   // (64,1,28,28)
    const float* __restrict__ rp,       // (4,)
    const float* __restrict__ fcw,      // (10,784)
    float* __restrict__ partials)       // (64,13,10)
{
  const int tid = threadIdx.x;
  const int B   = blockIdx.x;
  const int b   = B / 13;               // image
  const int sb  = B - b * 13;           // sub-block within image
  const int grp = tid >> 4;
  const int l16 = tid & 15;
  const int pi  = sb * 16 + grp;        // patch index (0..207; active if <196)
  const bool active = (pi < 196);

  // Per-lane parity table: bit_m(P) = parity(l16 & m).
  unsigned P = 0;
  if (l16 & 1) P ^= 0xAAAAu;
  if (l16 & 2) P ^= 0xCCCCu;
  if (l16 & 4) P ^= 0xF0F0u;
  if (l16 & 8) P ^= 0xFF00u;

  float re = (l16 == 0) ? 1.f : 0.f;
  float im = 0.f;

  if (active) {
    const int pj = pi / 14;
    const int pk = pi - pj * 14;
    const float* img = images + b * 784 + (2 * pj) * 28 + 2 * pk;
    float px[4];
    px[0] = img[0]  * PI_F;
    px[1] = img[1]  * PI_F;
    px[2] = img[28] * PI_F;
    px[3] = img[29] * PI_F;

    // 4 distinct Rot matrices (GROUP_IDX period 4).
    float wr[4], wi[4], xr[4], xi[4];
    {
      const int GIphi[4] = {0, 3, 2, 1};
      const int GIth [4] = {1, 0, 3, 2};
      const int GIom [4] = {2, 1, 0, 3};
#pragma unroll
      for (int g = 0; g < 4; ++g) {
        const float phi = px[GIphi[g]], th = px[GIth[g]], om = px[GIom[g]];
        const float a = 0.5f * (phi + om), d = 0.5f * (phi - om), h = 0.5f * th;
        const float sa = __sinf(a), ca = __cosf(a);
        const float sd = __sinf(d), cd = __cosf(d);
        const float st = __sinf(h), ct = __cosf(h);
        wr[g] =  ca * ct;  wi[g] = -sa * ct;   // u00
        xr[g] = -cd * st;  xi[g] = -sd * st;   // u01
      }
    }

    Loop80<0>::run(re, im, P, wr, wi, xr, xi);

    // Final gates 80..83: RX(rp0)@3, RY(rp1)@1, RZ(rp2)@0, RX(rp3)@2.
    {
      const float s0 = __sinf(0.5f * rp[0]), c0 = __cosf(0.5f * rp[0]);
      apply_gate<GT.xm[80], GT.sm[80]>(re, im, P, c0, 0.f, 0.f, -s0);
      const float s1 = __sinf(0.5f * rp[1]), c1 = __cosf(0.5f * rp[1]);
      apply_gate<GT.xm[81], GT.sm[81]>(re, im, P, c1, 0.f, -s1, 0.f);
      const float s2 = __sinf(0.5f * rp[2]), c2 = __cosf(0.5f * rp[2]);
      apply_gate<GT.xm[82], GT.sm[82]>(re, im, P, c2, -s2, 0.f, 0.f);
      const float s3 = __sinf(0.5f * rp[3]), c3 = __cosf(0.5f * rp[3]);
      apply_gate<GT.xm[83], GT.sm[83]>(re, im, P, c3, 0.f, 0.f, -s3);
    }
  }

  // ---- FC fold: lane contributes pr * sign_j(l) * w[o][pi*4+j] ------------
  // pj_j = pr with sign bit parity(l & fin[3-j])  (the old e_j pre-reduce).
  const float pr = active ? (re * re + im * im) : 0.f;
  const float pj0 = __uint_as_float(__float_as_uint(pr) ^ (((P >> GT.fin[3]) & 1u) << 31));
  const float pj1 = __uint_as_float(__float_as_uint(pr) ^ (((P >> GT.fin[2]) & 1u) << 31));
  const float pj2 = __uint_as_float(__float_as_uint(pr) ^ (((P >> GT.fin[1]) & 1u) << 31));
  const float pj3 = __uint_as_float(__float_as_uint(pr) ^ (((P >> GT.fin[0]) & 1u) << 31));

  const int fidx4 = active ? pi * 4 : 0;   // 16B-aligned float4 index base
  float acc[10];
#pragma unroll
  for (int o = 0; o < 10; ++o) {
    const float4 w4 = *reinterpret_cast<const float4*>(fcw + o * 784 + fidx4);
    acc[o] = pj0 * w4.x + pj1 * w4.y + pj2 * w4.z + pj3 * w4.w;
  }

  // 16-lane reduce entirely on VALU: xor1, xor2, xor7, xor15 folds.
#pragma unroll
  for (int o = 0; o < 10; ++o) {
    acc[o] += dppmov<0xB1>(acc[o]);    // xor1
    acc[o] += dppmov<0x4E>(acc[o]);    // xor2
    acc[o] += dppmov<0x141>(acc[o]);   // xor7 (quads uniform -> folds bit2)
    acc[o] += dppmov<0x140>(acc[o]);   // xor15 (octets uniform -> folds bit3)
  }

  // Each 16-lane row writes its 10 row-sums; finisher sums 16 rows.
  __shared__ float wrow[16][10];
  const int row = tid >> 4;
#pragma unroll
  for (int o = 0; o < 10; ++o)
    if (l16 == o) wrow[row][o] = acc[o];
  __syncthreads();

  if (tid < 10) {
    float s = 0.f;
#pragma unroll
    for (int r = 0; r < 16; ++r) s += wrow[r][tid];
    partials[(b * 13 + sb) * 10 + tid] = s;   // plain store, stream-ordered
  }
}

// ---------------------------------------------------------------------------
// Finisher: sum 13 partials per (image, class), bias, log_softmax.
// ---------------------------------------------------------------------------
__global__ __launch_bounds__(64) void qcnn_fc_kernel(
    const float* __restrict__ partials,  // (64,13,10)
    const float* __restrict__ fcb,       // (10,)
    float* __restrict__ out)             // (64,10)
{
  const int b   = blockIdx.x;
  const int tid = threadIdx.x;
  if (tid >= 16) return;

  float lgv = -1e30f;
  if (tid < 10) {
    float s = fcb[tid];
#pragma unroll
    for (int k = 0; k < 13; ++k) s += partials[(b * 13 + k) * 10 + tid];
    lgv = s;
  }
  float mx = lgv;
#pragma unroll
  for (int s = 1; s < 16; s <<= 1) mx = fmaxf(mx, __shfl_xor(mx, s));
  float ex = (tid < 10) ? __expf(lgv - mx) : 0.f;
  float se = ex;
#pragma unroll
  for (int s = 1; s < 16; s <<= 1) se += __shfl_xor(se, s);
  if (tid < 10) out[b * 10 + tid] = lgv - mx - __logf(se);
}

// ---------------------------------------------------------------------------

extern "C" void kernel_launch(void* const* d_in, const int* in_sizes, int n_in,
                              void* d_out, int out_size, void* d_ws, size_t ws_size,
                              hipStream_t stream) {
  const float* images = (const float*)d_in[0];   // 64*1*28*28
  const float* rp     = (const float*)d_in[1];   // 4
  const float* fcw    = (const float*)d_in[2];   // 10*784
  const float* fcb    = (const float*)d_in[3];   // 10
  float* out = (float*)d_out;                    // 64*10
  float* partials = (float*)d_ws;                // 64*13*10 floats = 33 KB

  qcnn_circuit_kernel<<<832, 256, 0, stream>>>(images, rp, fcw, partials);
  qcnn_fc_kernel<<<64, 64, 0, stream>>>(partials, fcb, out);
}

// Round 7
// 18.320 us; speedup vs baseline: 2.3875x; 1.1420x over previous
//
#include <hip/hip_runtime.h>
#include <math.h>

#define PI_F 3.14159265358979323846f

// ---------------------------------------------------------------------------
// Amplitude-per-lane 4-qubit simulator (DPP shuffles) + separate tiny FC.
//
// 16 lanes = 1 circuit; lane holds ONE complex amplitude. CNOTs fold into a
// compile-time lane relabeling f (GF(2)-linear); gate k exchanges with lane
// l ^ xm[k] and sign-selects by parity(l & sm[k]).
//
// ROUND-7: recombination of measured wins. Round-2 lean structure (no FC
// tail in kernel 1 — the r5/r6 tail cost ~2us: redundant per-thread weight
// loads + LDS round-trip + barrier) + round-6 DPP lane exchanges (verified
// bit-exact, worth ~0.7us over ds_swizzle __shfl_xor). Gate masks {9,10,11}
// stay on the LDS pipe for pipe balance; all other exchanges and the final
// 16-lane ev-reduce run on the VALU via DPP.
// ---------------------------------------------------------------------------

struct Gates { int xm[84]; int sm[84]; int fin[4]; };

constexpr Gates make_gates() {
  Gates gt{};
  int F[4] = {1, 2, 4, 8};   // F[p]: bit_p(f(l)) = parity(l & F[p])
  int H[4] = {1, 2, 4, 8};   // rows of f^{-1}
  int ng = 0;
  auto cnot = [&](int c, int t) {
    const int pc = 3 - c, pt = 3 - t;
    F[pt] ^= F[pc];
    for (int p = 0; p < 4; ++p)
      if (H[p] & (1 << pt)) H[p] ^= (1 << pc);
  };
  auto gate = [&](int w) {
    const int p = 3 - w;
    int m = 0;
    for (int q = 0; q < 4; ++q)
      if (H[q] & (1 << p)) m |= 1 << q;   // m = f^{-1}(e_p)
    gt.xm[ng] = m; gt.sm[ng] = F[p]; ++ng;
  };
  for (int step = 0; step < 20; ++step)
    for (int j = 0; j < 4; ++j) {
      gate(j);
      cnot(0, 1); cnot(1, 2); cnot(2, 3); cnot(3, 0);
    }
  // RandomLayers stand-in: rx@3, ry@1, CNOT(0,2), rz@0, rx@2, CNOT(1,3)
  gate(3); gate(1); cnot(0, 2); gate(0); gate(2); cnot(1, 3);
  for (int p = 0; p < 4; ++p) gt.fin[p] = F[p];
  return gt;
}

constexpr Gates GT = make_gates();

// ---- DPP-based xor-shuffle (VALU pipe) ------------------------------------
template <int CTRL>
__device__ __forceinline__ float dppmov(float v) {
  return __int_as_float(
      __builtin_amdgcn_mov_dpp(__float_as_int(v), CTRL, 0xF, 0xF, true));
}

// xor-exchange across lanes. bit3 -> row_mirror(xor15), bit2 ->
// row_half_mirror(xor7), residual {1,2,3} -> quad_perm.
// {9,10,11} (3-chain) stay on the LDS pipe (__shfl_xor) for pipe balance.
template <int M>
__device__ __forceinline__ float sxor(float v) {
  if constexpr (M == 0) return v;
  else if constexpr (M == 9 || M == 10 || M == 11) return __shfl_xor(v, M);
  else if constexpr ((M & 8) != 0) return sxor<M ^ 15>(dppmov<0x140>(v)); // xor15
  else if constexpr ((M & 4) != 0) return sxor<M ^ 7>(dppmov<0x141>(v));  // xor7
  else if constexpr (M == 1) return dppmov<0xB1>(v);   // quad_perm [1,0,3,2]
  else if constexpr (M == 2) return dppmov<0x4E>(v);   // quad_perm [2,3,0,1]
  else return dppmov<0x1B>(v);                          // quad_perm [3,2,1,0]
}

// Rot-symmetric gate: u00=(WR,WI), u01=(XR,XI), u10=(-XR,XI), u11=(WR,-WI).
template <int XM, int SM>
__device__ __forceinline__ void apply_gate(float& re, float& im, unsigned P,
                                           float WR, float WI, float XR, float XI) {
  const float pre = sxor<XM>(re);
  const float pim = sxor<XM>(im);
  const unsigned sb = ((P >> SM) & 1u) << 31;
  const float cmi = __uint_as_float(__float_as_uint(WI) ^ sb);
  const float cpr = __uint_as_float(__float_as_uint(XR) ^ sb);
  const float nre = WR * re - cmi * im + cpr * pre - XI * pim;
  const float nim = WR * im + cmi * re + cpr * pim + XI * pre;
  re = nre; im = nim;
}

// Compile-time-unrolled 80-gate main loop (masks must be template args).
template <int K>
struct Loop80 {
  static __device__ __forceinline__ void run(float& re, float& im, unsigned P,
      const float (&wr)[4], const float (&wi)[4],
      const float (&xr)[4], const float (&xi)[4]) {
    constexpr int g = (K >> 2) & 3;
    apply_gate<GT.xm[K], GT.sm[K]>(re, im, P, wr[g], wi[g], xr[g], xi[g]);
    Loop80<K + 1>::run(re, im, P, wr, wi, xr, xi);
  }
};
template <>
struct Loop80<80> {
  static __device__ __forceinline__ void run(float&, float&, unsigned,
      const float (&)[4], const float (&)[4],
      const float (&)[4], const float (&)[4]) {}
};

__global__ __launch_bounds__(256) void qcnn_circuit_kernel(
    const float* __restrict__ images,   // (64,1,28,28)
    const float* __restrict__ rp,       // (4,)
    float* __restrict__ qout)           // (64*196*4,)
{
  const int gtid = blockIdx.x * 256 + threadIdx.x;
  const int c    = gtid >> 4;          // circuit id, 0..12543
  const int l16  = gtid & 15;          // lane within circuit = initial amp idx

  const int b  = c / 196;
  const int pi = c - b * 196;
  const int pj = pi / 14;
  const int pk = pi - pj * 14;

  const float* img = images + b * 784 + (2 * pj) * 28 + 2 * pk;
  const float2 r0 = *reinterpret_cast<const float2*>(img);
  const float2 r1 = *reinterpret_cast<const float2*>(img + 28);
  float px[4];
  px[0] = r0.x * PI_F;
  px[1] = r0.y * PI_F;
  px[2] = r1.x * PI_F;
  px[3] = r1.y * PI_F;

  // Per-lane parity table: bit_m(P) = parity(l16 & m).
  unsigned P = 0;
  if (l16 & 1) P ^= 0xAAAAu;
  if (l16 & 2) P ^= 0xCCCCu;
  if (l16 & 4) P ^= 0xF0F0u;
  if (l16 & 8) P ^= 0xFF00u;

  // 4 distinct Rot matrices (GROUP_IDX period 4).
  float wr[4], wi[4], xr[4], xi[4];
  {
    const int GIphi[4] = {0, 3, 2, 1};
    const int GIth [4] = {1, 0, 3, 2};
    const int GIom [4] = {2, 1, 0, 3};
#pragma unroll
    for (int g = 0; g < 4; ++g) {
      const float phi = px[GIphi[g]], th = px[GIth[g]], om = px[GIom[g]];
      const float a = 0.5f * (phi + om), d = 0.5f * (phi - om), h = 0.5f * th;
      const float sa = __sinf(a), ca = __cosf(a);
      const float sd = __sinf(d), cd = __cosf(d);
      const float st = __sinf(h), ct = __cosf(h);
      wr[g] =  ca * ct;  wi[g] = -sa * ct;   // u00
      xr[g] = -cd * st;  xi[g] = -sd * st;   // u01
    }
  }

  float re = (l16 == 0) ? 1.f : 0.f;
  float im = 0.f;

  Loop80<0>::run(re, im, P, wr, wi, xr, xi);

  // Final gates 80..83: RX(rp0)@3, RY(rp1)@1, RZ(rp2)@0, RX(rp3)@2.
  {
    const float s0 = __sinf(0.5f * rp[0]), c0 = __cosf(0.5f * rp[0]);
    apply_gate<GT.xm[80], GT.sm[80]>(re, im, P, c0, 0.f, 0.f, -s0);
    const float s1 = __sinf(0.5f * rp[1]), c1 = __cosf(0.5f * rp[1]);
    apply_gate<GT.xm[81], GT.sm[81]>(re, im, P, c1, 0.f, -s1, 0.f);
    const float s2 = __sinf(0.5f * rp[2]), c2 = __cosf(0.5f * rp[2]);
    apply_gate<GT.xm[82], GT.sm[82]>(re, im, P, c2, -s2, 0.f, 0.f);
    const float s3 = __sinf(0.5f * rp[3]), c3 = __cosf(0.5f * rp[3]);
    apply_gate<GT.xm[83], GT.sm[83]>(re, im, P, c3, 0.f, 0.f, -s3);
  }

  // PauliZ expvals; sign for wire j = parity(l & fin[3-j]).
  const float pr = re * re + im * im;
  float e0 = __uint_as_float(__float_as_uint(pr) ^ (((P >> GT.fin[3]) & 1u) << 31));
  float e1 = __uint_as_float(__float_as_uint(pr) ^ (((P >> GT.fin[2]) & 1u) << 31));
  float e2 = __uint_as_float(__float_as_uint(pr) ^ (((P >> GT.fin[1]) & 1u) << 31));
  float e3 = __uint_as_float(__float_as_uint(pr) ^ (((P >> GT.fin[0]) & 1u) << 31));
  // 16-lane reduce on VALU: after folding xor1,xor2 the quads are uniform,
  // so xor7 folds bit2 and xor15 folds bit3 (single DPP mov each).
#pragma unroll
  for (int q = 0; q < 1; ++q) {
    e0 += dppmov<0xB1>(e0); e0 += dppmov<0x4E>(e0); e0 += dppmov<0x141>(e0); e0 += dppmov<0x140>(e0);
    e1 += dppmov<0xB1>(e1); e1 += dppmov<0x4E>(e1); e1 += dppmov<0x141>(e1); e1 += dppmov<0x140>(e1);
    e2 += dppmov<0xB1>(e2); e2 += dppmov<0x4E>(e2); e2 += dppmov<0x141>(e2); e2 += dppmov<0x140>(e2);
    e3 += dppmov<0xB1>(e3); e3 += dppmov<0x4E>(e3); e3 += dppmov<0x141>(e3); e3 += dppmov<0x140>(e3);
  }
  float v = e0;
  v = (l16 == 1) ? e1 : v;
  v = (l16 == 2) ? e2 : v;
  v = (l16 == 3) ? e3 : v;
  if (l16 < 4) qout[c * 4 + l16] = v;
}

// ---------------------------------------------------------------------------
// FC (10x784) + log_softmax. One wave per image, float4 loads. (r2 verbatim)
// ---------------------------------------------------------------------------
__global__ __launch_bounds__(64) void qcnn_fc_kernel(
    const float* __restrict__ q,     // (64,784)
    const float* __restrict__ fcw,   // (10,784)
    const float* __restrict__ fcb,   // (10,)
    float* __restrict__ out)         // (64,10)
{
  const int b    = blockIdx.x;
  const int lane = threadIdx.x;
  const float4* q4 = reinterpret_cast<const float4*>(q + b * 784);
  const float4* w4 = reinterpret_cast<const float4*>(fcw);

  float acc[10];
#pragma unroll
  for (int o = 0; o < 10; ++o) acc[o] = 0.f;

  for (int i = lane; i < 196; i += 64) {
    const float4 qv = q4[i];
#pragma unroll
    for (int o = 0; o < 10; ++o) {
      const float4 wv = w4[o * 196 + i];
      acc[o] += qv.x * wv.x + qv.y * wv.y + qv.z * wv.z + qv.w * wv.w;
    }
  }

#pragma unroll
  for (int o = 0; o < 10; ++o) {
    for (int off = 32; off > 0; off >>= 1)
      acc[o] += __shfl_down(acc[o], off);
  }

  if (lane == 0) {
    float logits[10];
    float mx = -1e30f;
#pragma unroll
    for (int o = 0; o < 10; ++o) {
      logits[o] = acc[o] + fcb[o];
      mx = fmaxf(mx, logits[o]);
    }
    float se = 0.f;
#pragma unroll
    for (int o = 0; o < 10; ++o) se += __expf(logits[o] - mx);
    const float lse = mx + __logf(se);
#pragma unroll
    for (int o = 0; o < 10; ++o) out[b * 10 + o] = logits[o] - lse;
  }
}

// ---------------------------------------------------------------------------

extern "C" void kernel_launch(void* const* d_in, const int* in_sizes, int n_in,
                              void* d_out, int out_size, void* d_ws, size_t ws_size,
                              hipStream_t stream) {
  const float* images = (const float*)d_in[0];   // 64*1*28*28
  const float* rp     = (const float*)d_in[1];   // 4
  const float* fcw    = (const float*)d_in[2];   // 10*784
  const float* fcb    = (const float*)d_in[3];   // 10
  float* out = (float*)d_out;                    // 64*10
  float* q   = (float*)d_ws;                     // 64*196*4 floats

  // 12544 circuits x 16 lanes = 200704 threads = 784 blocks x 256
  qcnn_circuit_kernel<<<784, 256, 0, stream>>>(images, rp, q);
  qcnn_fc_kernel<<<64, 64, 0, stream>>>(q, fcw, fcb, out);
}

// Round 8
// 15.905 us; speedup vs baseline: 2.7500x; 1.1518x over previous
//
#include <hip/hip_runtime.h>
#include <math.h>

#define PI_F 3.14159265358979323846f

// ---------------------------------------------------------------------------
// Amplitude-per-lane 4-qubit simulator (DPP exchanges + packed VOP3P math)
// + separate widened FC kernel.
//
// 16 lanes = 1 circuit; lane holds ONE complex amplitude. CNOTs fold into a
// compile-time lane relabeling f (GF(2)-linear); gate k exchanges with lane
// l ^ xm[k] and sign-selects by parity(l & sm[k]).
//
// ROUND-8:
//  * gate core 8 scalar FMAs -> 4 VOP3P packed ops (v_pk_mul/fma_f32), with
//    the (im,re)/(pim,pre) swaps and the +/- sign pattern expressed via
//    op_sel / op_sel_hi / neg_lo modifiers (no extra movs).
//  * k1 blocks 256 -> 64 threads: 3136 1-wave blocks balance to ~3.25
//    waves/SIMD max instead of 4 (straggler CUs with 256-thread blocks).
//  * k2 widened to 256 threads: one float4 q-load round instead of 4.
// ---------------------------------------------------------------------------

struct Gates { int xm[84]; int sm[84]; int fin[4]; };

constexpr Gates make_gates() {
  Gates gt{};
  int F[4] = {1, 2, 4, 8};   // F[p]: bit_p(f(l)) = parity(l & F[p])
  int H[4] = {1, 2, 4, 8};   // rows of f^{-1}
  int ng = 0;
  auto cnot = [&](int c, int t) {
    const int pc = 3 - c, pt = 3 - t;
    F[pt] ^= F[pc];
    for (int p = 0; p < 4; ++p)
      if (H[p] & (1 << pt)) H[p] ^= (1 << pc);
  };
  auto gate = [&](int w) {
    const int p = 3 - w;
    int m = 0;
    for (int q = 0; q < 4; ++q)
      if (H[q] & (1 << p)) m |= 1 << q;   // m = f^{-1}(e_p)
    gt.xm[ng] = m; gt.sm[ng] = F[p]; ++ng;
  };
  for (int step = 0; step < 20; ++step)
    for (int j = 0; j < 4; ++j) {
      gate(j);
      cnot(0, 1); cnot(1, 2); cnot(2, 3); cnot(3, 0);
    }
  // RandomLayers stand-in: rx@3, ry@1, CNOT(0,2), rz@0, rx@2, CNOT(1,3)
  gate(3); gate(1); cnot(0, 2); gate(0); gate(2); cnot(1, 3);
  for (int p = 0; p < 4; ++p) gt.fin[p] = F[p];
  return gt;
}

constexpr Gates GT = make_gates();

// ---- DPP-based xor-shuffle (VALU pipe) ------------------------------------
template <int CTRL>
__device__ __forceinline__ float dppmov(float v) {
  return __int_as_float(
      __builtin_amdgcn_mov_dpp(__float_as_int(v), CTRL, 0xF, 0xF, true));
}

// xor-exchange across lanes. bit3 -> row_mirror(xor15), bit2 ->
// row_half_mirror(xor7), residual {1,2,3} -> quad_perm.
// {9,10,11} (LDS) kept for pipe balance, as measured in r6/r7.
template <int M>
__device__ __forceinline__ float sxor(float v) {
  if constexpr (M == 0) return v;
  else if constexpr (M == 9 || M == 10 || M == 11) return __shfl_xor(v, M);
  else if constexpr ((M & 8) != 0) return sxor<M ^ 15>(dppmov<0x140>(v)); // xor15
  else if constexpr ((M & 4) != 0) return sxor<M ^ 7>(dppmov<0x141>(v));  // xor7
  else if constexpr (M == 1) return dppmov<0xB1>(v);   // quad_perm [1,0,3,2]
  else if constexpr (M == 2) return dppmov<0x4E>(v);   // quad_perm [2,3,0,1]
  else return dppmov<0x1B>(v);                          // quad_perm [3,2,1,0]
}

// Rot-symmetric gate: u00=(WR,WI), u01=(XR,XI), u10=(-XR,XI), u11=(WR,-WI).
//   nre = WR*re - cmi*im + cpr*pre - XI*pim
//   nim = WR*im + cmi*re + cpr*pim + XI*pre     (cmi=WI^sb, cpr=XR^sb)
// Packed form (lo=nre, hi=nim), S=(re,im) P2=(pre,pim) WX=(WR,XI) CC=(cmi,cpr):
//   d  = pk_mul(S, WX)        op_sel[0,0]  op_sel_hi[1,0]   (WR*re, WR*im)
//   d += pk_fma(S, CC, d)     op_sel[1,0,0] op_sel_hi[0,0,1] neg_lo[0,1,0]
//                                                     (-cmi*im, +cmi*re)
//   d += pk_fma(P2, CC, d)    op_sel[0,1,0] op_sel_hi[1,1,1] (cpr*pre, cpr*pim)
//   d += pk_fma(P2, WX, d)    op_sel[1,1,0] op_sel_hi[0,1,1] neg_lo[0,1,0]
//                                                     (-XI*pim, +XI*pre)
template <int XM, int SM>
__device__ __forceinline__ void apply_gate(float& re, float& im, unsigned P,
                                           float WR, float WI, float XR, float XI) {
  const float pre = sxor<XM>(re);
  const float pim = sxor<XM>(im);
  const unsigned sb = ((P >> SM) & 1u) << 31;
  float2 s;  s.x = re;   s.y = im;
  float2 p2; p2.x = pre; p2.y = pim;
  float2 wx; wx.x = WR;  wx.y = XI;
  float2 cc;
  cc.x = __uint_as_float(__float_as_uint(WI) ^ sb);
  cc.y = __uint_as_float(__float_as_uint(XR) ^ sb);
  float2 d;
  asm("v_pk_mul_f32 %0, %1, %3 op_sel:[0,0] op_sel_hi:[1,0]\n\t"
      "v_pk_fma_f32 %0, %1, %4, %0 op_sel:[1,0,0] op_sel_hi:[0,0,1] neg_lo:[0,1,0]\n\t"
      "v_pk_fma_f32 %0, %2, %4, %0 op_sel:[0,1,0] op_sel_hi:[1,1,1]\n\t"
      "v_pk_fma_f32 %0, %2, %3, %0 op_sel:[1,1,0] op_sel_hi:[0,1,1] neg_lo:[0,1,0]"
      : "=&v"(d)
      : "v"(s), "v"(p2), "v"(wx), "v"(cc));
  re = d.x; im = d.y;
}

// Compile-time-unrolled 80-gate main loop (masks must be template args).
template <int K>
struct Loop80 {
  static __device__ __forceinline__ void run(float& re, float& im, unsigned P,
      const float (&wr)[4], const float (&wi)[4],
      const float (&xr)[4], const float (&xi)[4]) {
    constexpr int g = (K >> 2) & 3;
    apply_gate<GT.xm[K], GT.sm[K]>(re, im, P, wr[g], wi[g], xr[g], xi[g]);
    Loop80<K + 1>::run(re, im, P, wr, wi, xr, xi);
  }
};
template <>
struct Loop80<80> {
  static __device__ __forceinline__ void run(float&, float&, unsigned,
      const float (&)[4], const float (&)[4],
      const float (&)[4], const float (&)[4]) {}
};

__global__ __launch_bounds__(64) void qcnn_circuit_kernel(
    const float* __restrict__ images,   // (64,1,28,28)
    const float* __restrict__ rp,       // (4,)
    float* __restrict__ qout)           // (64*196*4,)
{
  const int gtid = blockIdx.x * 64 + threadIdx.x;
  const int c    = gtid >> 4;          // circuit id, 0..12543
  const int l16  = gtid & 15;          // lane within circuit = initial amp idx

  const int b  = c / 196;
  const int pi = c - b * 196;
  const int pj = pi / 14;
  const int pk = pi - pj * 14;

  const float* img = images + b * 784 + (2 * pj) * 28 + 2 * pk;
  const float2 r0 = *reinterpret_cast<const float2*>(img);
  const float2 r1 = *reinterpret_cast<const float2*>(img + 28);
  float px[4];
  px[0] = r0.x * PI_F;
  px[1] = r0.y * PI_F;
  px[2] = r1.x * PI_F;
  px[3] = r1.y * PI_F;

  // Per-lane parity table: bit_m(P) = parity(l16 & m).
  unsigned P = 0;
  if (l16 & 1) P ^= 0xAAAAu;
  if (l16 & 2) P ^= 0xCCCCu;
  if (l16 & 4) P ^= 0xF0F0u;
  if (l16 & 8) P ^= 0xFF00u;

  // 4 distinct Rot matrices (GROUP_IDX period 4).
  float wr[4], wi[4], xr[4], xi[4];
  {
    const int GIphi[4] = {0, 3, 2, 1};
    const int GIth [4] = {1, 0, 3, 2};
    const int GIom [4] = {2, 1, 0, 3};
#pragma unroll
    for (int g = 0; g < 4; ++g) {
      const float phi = px[GIphi[g]], th = px[GIth[g]], om = px[GIom[g]];
      const float a = 0.5f * (phi + om), d = 0.5f * (phi - om), h = 0.5f * th;
      const float sa = __sinf(a), ca = __cosf(a);
      const float sd = __sinf(d), cd = __cosf(d);
      const float st = __sinf(h), ct = __cosf(h);
      wr[g] =  ca * ct;  wi[g] = -sa * ct;   // u00
      xr[g] = -cd * st;  xi[g] = -sd * st;   // u01
    }
  }

  float re = (l16 == 0) ? 1.f : 0.f;
  float im = 0.f;

  Loop80<0>::run(re, im, P, wr, wi, xr, xi);

  // Final gates 80..83: RX(rp0)@3, RY(rp1)@1, RZ(rp2)@0, RX(rp3)@2.
  {
    const float s0 = __sinf(0.5f * rp[0]), c0 = __cosf(0.5f * rp[0]);
    apply_gate<GT.xm[80], GT.sm[80]>(re, im, P, c0, 0.f, 0.f, -s0);
    const float s1 = __sinf(0.5f * rp[1]), c1 = __cosf(0.5f * rp[1]);
    apply_gate<GT.xm[81], GT.sm[81]>(re, im, P, c1, 0.f, -s1, 0.f);
    const float s2 = __sinf(0.5f * rp[2]), c2 = __cosf(0.5f * rp[2]);
    apply_gate<GT.xm[82], GT.sm[82]>(re, im, P, c2, -s2, 0.f, 0.f);
    const float s3 = __sinf(0.5f * rp[3]), c3 = __cosf(0.5f * rp[3]);
    apply_gate<GT.xm[83], GT.sm[83]>(re, im, P, c3, 0.f, 0.f, -s3);
  }

  // PauliZ expvals; sign for wire j = parity(l & fin[3-j]).
  const float pr = re * re + im * im;
  float e0 = __uint_as_float(__float_as_uint(pr) ^ (((P >> GT.fin[3]) & 1u) << 31));
  float e1 = __uint_as_float(__float_as_uint(pr) ^ (((P >> GT.fin[2]) & 1u) << 31));
  float e2 = __uint_as_float(__float_as_uint(pr) ^ (((P >> GT.fin[1]) & 1u) << 31));
  float e3 = __uint_as_float(__float_as_uint(pr) ^ (((P >> GT.fin[0]) & 1u) << 31));
  // 16-lane reduce on VALU: after folding xor1,xor2 the quads are uniform,
  // so xor7 folds bit2 and xor15 folds bit3 (single DPP mov each).
  e0 += dppmov<0xB1>(e0); e0 += dppmov<0x4E>(e0); e0 += dppmov<0x141>(e0); e0 += dppmov<0x140>(e0);
  e1 += dppmov<0xB1>(e1); e1 += dppmov<0x4E>(e1); e1 += dppmov<0x141>(e1); e1 += dppmov<0x140>(e1);
  e2 += dppmov<0xB1>(e2); e2 += dppmov<0x4E>(e2); e2 += dppmov<0x141>(e2); e2 += dppmov<0x140>(e2);
  e3 += dppmov<0xB1>(e3); e3 += dppmov<0x4E>(e3); e3 += dppmov<0x141>(e3); e3 += dppmov<0x140>(e3);
  float v = e0;
  v = (l16 == 1) ? e1 : v;
  v = (l16 == 2) ? e2 : v;
  v = (l16 == 3) ? e3 : v;
  if (l16 < 4) qout[c * 4 + l16] = v;
}

// ---------------------------------------------------------------------------
// FC (10x784) + log_softmax. One block (256 threads) per image:
// thread t<196 handles one float4 chunk -> single load round.
// ---------------------------------------------------------------------------
__global__ __launch_bounds__(256) void qcnn_fc_kernel(
    const float* __restrict__ q,     // (64,784)
    const float* __restrict__ fcw,   // (10,784)
    const float* __restrict__ fcb,   // (10,)
    float* __restrict__ out)         // (64,10)
{
  const int b = blockIdx.x;
  const int t = threadIdx.x;

  float acc[10];
#pragma unroll
  for (int o = 0; o < 10; ++o) acc[o] = 0.f;

  if (t < 196) {
    const float4 qv = reinterpret_cast<const float4*>(q + b * 784)[t];
    const float4* w4 = reinterpret_cast<const float4*>(fcw);
#pragma unroll
    for (int o = 0; o < 10; ++o) {
      const float4 wv = w4[o * 196 + t];
      acc[o] += qv.x * wv.x + qv.y * wv.y + qv.z * wv.z + qv.w * wv.w;
    }
  }

  // 64-lane wave reduce.
#pragma unroll
  for (int o = 0; o < 10; ++o) {
#pragma unroll
    for (int off = 32; off > 0; off >>= 1)
      acc[o] += __shfl_xor(acc[o], off);
  }

  __shared__ float ws[4][10];
  const int wid = t >> 6;
  if ((t & 63) == 0) {
#pragma unroll
    for (int o = 0; o < 10; ++o) ws[wid][o] = acc[o];
  }
  __syncthreads();

  if (t < 16) {
    float lgv = -1e30f;
    if (t < 10)
      lgv = ws[0][t] + ws[1][t] + ws[2][t] + ws[3][t] + fcb[t];
    float mx = lgv;
#pragma unroll
    for (int s = 1; s < 16; s <<= 1) mx = fmaxf(mx, __shfl_xor(mx, s));
    float ex = (t < 10) ? __expf(lgv - mx) : 0.f;
    float se = ex;
#pragma unroll
    for (int s = 1; s < 16; s <<= 1) se += __shfl_xor(se, s);
    if (t < 10) out[b * 10 + t] = lgv - mx - __logf(se);
  }
}

// ---------------------------------------------------------------------------

extern "C" void kernel_launch(void* const* d_in, const int* in_sizes, int n_in,
                              void* d_out, int out_size, void* d_ws, size_t ws_size,
                              hipStream_t stream) {
  const float* images = (const float*)d_in[0];   // 64*1*28*28
  const float* rp     = (const float*)d_in[1];   // 4
  const float* fcw    = (const float*)d_in[2];   // 10*784
  const float* fcb    = (const float*)d_in[3];   // 10
  float* out = (float*)d_out;                    // 64*10
  float* q   = (float*)d_ws;                     // 64*196*4 floats

  // 12544 circuits x 16 lanes = 200704 threads = 3136 blocks x 64
  qcnn_circuit_kernel<<<3136, 64, 0, stream>>>(images, rp, q);
  qcnn_fc_kernel<<<64, 256, 0, stream>>>(q, fcw, fcb, out);
}